// Round 7
// baseline (224.733 us; speedup 1.0000x reference)
//
#include <hip/hip_runtime.h>

typedef unsigned short ushort_t;
using f32x4   = __attribute__((ext_vector_type(4))) float;
using f32x16  = __attribute__((ext_vector_type(16))) float;
using bf16x8  = __attribute__((ext_vector_type(8))) __bf16;

typedef __attribute__((address_space(1))) const void gvoid_t;
typedef __attribute__((address_space(3))) void svoid_t;

union Frag {
    uint4    u4;
    bf16x8   b;
    ushort_t s[8];
};

__device__ __forceinline__ ushort_t f2bf(float f) {
    union { float f; unsigned u; } a; a.f = f;
    unsigned u = a.u;
    unsigned r = (u + 0x7fffu + ((u >> 16) & 1u)) >> 16;   // RNE
    return (ushort_t)r;
}
__device__ __forceinline__ float bf2f(ushort_t b) {
    union { unsigned u; float f; } a; a.u = ((unsigned)b) << 16;
    return a.f;
}
__device__ __forceinline__ unsigned pack2bf(float lo, float hi) {
    union { __bf16 h[2]; unsigned u; } p;
    p.h[0] = (__bf16)lo;
    p.h[1] = (__bf16)hi;
    return p.u;
}
__device__ __forceinline__ float exp2_fast(float x) {
#if __has_builtin(__builtin_amdgcn_exp2f)
    return __builtin_amdgcn_exp2f(x);
#else
    return exp2f(x);
#endif
}
__device__ __forceinline__ float fmax3(float a, float b, float c) {
    return fmaxf(fmaxf(a, b), c);     // clang fuses to v_max3_f32
}
// v_permlane32_swap_b32: x' = [x.lo, y.lo], y' = [x.hi, y.hi]
__device__ __forceinline__ void pl32swap(unsigned &x, unsigned &y) {
#if __has_builtin(__builtin_amdgcn_permlane32_swap)
    auto r = __builtin_amdgcn_permlane32_swap((int)x, (int)y, false, false);
    x = (unsigned)r[0]; y = (unsigned)r[1];
#else
    asm volatile("v_permlane32_swap_b32 %0, %1" : "+v"(x), "+v"(y));
#endif
}
__device__ __forceinline__ f32x16 mfma32(bf16x8 a, bf16x8 b, f32x16 c) {
    return __builtin_amdgcn_mfma_f32_32x32x16_bf16(a, b, c, 0, 0, 0);
}

// LOG2E folded into q-prescale so softmax runs in exp2 domain
#define QSCALE 0.18033688011112042f   // 0.125 * log2(e)

// ---------------------------------------------------------------- LayerNorm
__global__ __launch_bounds__(256)
void ln_kernel(const float* __restrict__ x, const float* __restrict__ gamma,
               ushort_t* __restrict__ xn)
{
    const int row = blockIdx.x;
    const int tid = threadIdx.x;
    const float4 v = *reinterpret_cast<const float4*>(x + (size_t)row * 1024 + tid * 4);

    float s = v.x + v.y + v.z + v.w;
    float q = v.x * v.x + v.y * v.y + v.z * v.z + v.w * v.w;
    #pragma unroll
    for (int off = 1; off <= 32; off <<= 1) {
        s += __shfl_xor(s, off);
        q += __shfl_xor(q, off);
    }
    __shared__ float ss[4], sq[4];
    if ((tid & 63) == 0) { ss[tid >> 6] = s; sq[tid >> 6] = q; }
    __syncthreads();
    const float S  = ss[0] + ss[1] + ss[2] + ss[3];
    const float Q  = sq[0] + sq[1] + sq[2] + sq[3];
    const float mu = S * (1.0f / 1024.0f);
    const float var = Q * (1.0f / 1024.0f) - mu * mu;
    const float rstd = rsqrtf(var + 1e-5f);

    const float4 gm = *reinterpret_cast<const float4*>(gamma + tid * 4);
    ushort4 o;
    o.x = f2bf((v.x - mu) * rstd * gm.x);
    o.y = f2bf((v.y - mu) * rstd * gm.y);
    o.z = f2bf((v.z - mu) * rstd * gm.z);
    o.w = f2bf((v.w - mu) * rstd * gm.w);
    *reinterpret_cast<ushort4*>(xn + (size_t)row * 1024 + tid * 4) = o;
}

// ------------------------------------------- weight transpose fp32[K][N] -> bf16[N][K]
__global__ __launch_bounds__(256)
void wt_kernel(const float* __restrict__ w, ushort_t* __restrict__ wt, int K, int N)
{
    __shared__ float tile[32][33];
    const int n0 = blockIdx.x * 32, k0 = blockIdx.y * 32;
    const int tx = threadIdx.x, ty = threadIdx.y;   // (32, 8)
    #pragma unroll
    for (int i = 0; i < 4; ++i) {
        int r = ty + i * 8;
        tile[r][tx] = w[(size_t)(k0 + r) * N + n0 + tx];
    }
    __syncthreads();
    #pragma unroll
    for (int i = 0; i < 4; ++i) {
        int r = ty + i * 8;
        wt[(size_t)(n0 + r) * K + k0 + tx] = f2bf(tile[tx][r]);
    }
}

// ---------------------------------------------------------------- GEMM v3
// C[M,N] = A[M,1024](bf16) * Bt[N,1024](bf16)^T ; 128x128 tile, BK=64, 4 waves.
// DOUBLE-BUFFERED global_load_lds staging (minimum 2-phase): stage t+1 while
// computing t, ONE barrier per K-step. Linear LDS dest, inverse-swizzled source,
// XOR-swizzled ds_read_b128. grid(x=m-tile) keeps a bh's tiles on one XCD.
// MODE 0: fused QKV epilogue (q scaled -> o16a; k -> o16a+8388608; v^T -> o16b)
// MODE 2: fp32 row-major (o32)
__device__ __forceinline__ void gemm_stage(const ushort_t* const* asrc,
                                           const ushort_t* const* bsrc,
                                           ushort_t* dA, ushort_t* dB,
                                           int kt, int tid)
{
    #pragma unroll
    for (int j = 0; j < 4; ++j) {
        __builtin_amdgcn_global_load_lds((gvoid_t*)(asrc[j] + kt * 64),
                                         (svoid_t*)(&dA[(j * 256 + tid) * 8]), 16, 0, 0);
        __builtin_amdgcn_global_load_lds((gvoid_t*)(bsrc[j] + kt * 64),
                                         (svoid_t*)(&dB[(j * 256 + tid) * 8]), 16, 0, 0);
    }
}
__device__ __forceinline__ void gemm_comp(const ushort_t* bA, const ushort_t* bB,
                                          f32x4 (&acc)[4][4],
                                          int wm, int wn, int g, int c, int swz)
{
    #pragma unroll
    for (int kk = 0; kk < 2; ++kk) {
        Frag af[4], bfr[4];
        #pragma unroll
        for (int mi = 0; mi < 4; ++mi)
            af[mi].u4 = *reinterpret_cast<const uint4*>(
                &bA[(wm * 64 + mi * 16 + c) * 64 + ((((kk << 2) | g)) ^ swz) * 8]);
        #pragma unroll
        for (int ni = 0; ni < 4; ++ni)
            bfr[ni].u4 = *reinterpret_cast<const uint4*>(
                &bB[(wn * 64 + ni * 16 + c) * 64 + ((((kk << 2) | g)) ^ swz) * 8]);
        #pragma unroll
        for (int mi = 0; mi < 4; ++mi)
            #pragma unroll
            for (int ni = 0; ni < 4; ++ni)
                acc[mi][ni] = __builtin_amdgcn_mfma_f32_16x16x32_bf16(
                    af[mi].b, bfr[ni].b, acc[mi][ni], 0, 0, 0);
    }
}

template<int MODE>
__global__ __launch_bounds__(256)
void gemm_kernel(const ushort_t* __restrict__ A, const ushort_t* __restrict__ Bt,
                 ushort_t* __restrict__ o16a, ushort_t* __restrict__ o16b,
                 float* __restrict__ o32)
{
    __shared__ ushort_t ldsA[2][128 * 64];   // 2 x 16 KB
    __shared__ ushort_t ldsB[2][128 * 64];

    const int tid = threadIdx.x;
    const int m0 = blockIdx.x * 128, n0 = blockIdx.y * 128;
    const int w = tid >> 6, l = tid & 63, g = l >> 4, c = l & 15;
    const int wm = w >> 1, wn = w & 1;

    const ushort_t* asrc[4];
    const ushort_t* bsrc[4];
    #pragma unroll
    for (int j = 0; j < 4; ++j) {
        const int gidx = j * 256 + tid;
        const int row = gidx >> 3;
        const int sl  = (gidx & 7) ^ (row & 7);
        asrc[j] = A  + (size_t)(m0 + row) * 1024 + sl * 8;
        bsrc[j] = Bt + (size_t)(n0 + row) * 1024 + sl * 8;
    }

    f32x4 acc[4][4];
    #pragma unroll
    for (int mi = 0; mi < 4; ++mi)
        #pragma unroll
        for (int ni = 0; ni < 4; ++ni)
            acc[mi][ni] = (f32x4){0.f, 0.f, 0.f, 0.f};

    const int swz = c & 7;

    gemm_stage(asrc, bsrc, ldsA[0], ldsB[0], 0, tid);
    #pragma unroll 1
    for (int k2 = 0; k2 < 8; ++k2) {
        __syncthreads();                                   // stage(2k2) landed; prev reads done
        gemm_stage(asrc, bsrc, ldsA[1], ldsB[1], 2 * k2 + 1, tid);
        gemm_comp(ldsA[0], ldsB[0], acc, wm, wn, g, c, swz);
        __syncthreads();                                   // stage(2k2+1) landed
        if (k2 < 7) gemm_stage(asrc, bsrc, ldsA[0], ldsB[0], 2 * k2 + 2, tid);
        gemm_comp(ldsA[1], ldsB[1], acc, wm, wn, g, c, swz);
    }

    // epilogue:  rows m = mbase + r, col n;  D layout: row=(l>>4)*4+r, col=l&15
    #pragma unroll
    for (int mi = 0; mi < 4; ++mi) {
        const int mbase = m0 + wm * 64 + mi * 16 + g * 4;
        #pragma unroll
        for (int ni = 0; ni < 4; ++ni) {
            const int n = n0 + wn * 64 + ni * 16 + c;
            if (MODE == 0) {
                if (n < 2048) {                 // q (scaled) or k
                    const int nn = n & 1023;
                    const int hh = nn >> 6, d = nn & 63;
                    const size_t base = (n < 1024) ? 0 : 8388608;
                    const float scale = (n < 1024) ? QSCALE : 1.f;
                    #pragma unroll
                    for (int r = 0; r < 4; ++r) {
                        const int m = mbase + r;
                        const int b = m >> 11, tok = m & 2047;
                        o16a[base + (((size_t)b * 16 + hh) * 2048 + tok) * 64 + d] =
                            f2bf(acc[mi][ni][r] * scale);
                    }
                } else {                        // v, transposed store
                    const int nn = n - 2048;
                    const int hh = nn >> 6, d = nn & 63;
                    const int b = mbase >> 11, tok0 = mbase & 2047;
                    ushort4 pv;
                    pv.x = f2bf(acc[mi][ni][0]);
                    pv.y = f2bf(acc[mi][ni][1]);
                    pv.z = f2bf(acc[mi][ni][2]);
                    pv.w = f2bf(acc[mi][ni][3]);
                    *reinterpret_cast<ushort4*>(
                        o16b + (((size_t)b * 16 + hh) * 64 + d) * 2048 + tok0) = pv;
                }
            } else {
                #pragma unroll
                for (int r = 0; r < 4; ++r)
                    o32[(size_t)(mbase + r) * 1024 + n] = acc[mi][ni][r];
            }
        }
    }
}

// ---------------------------------------------------------------- flash attention v7
// 32x32x16 MFMA. grid (64 bh, 16 qb); 4 waves x 32 q-rows = 128 q/block
// -> 1024 blocks = 4/CU x 256 CU, one clean round. K/V LDS-staged
// (global_load_lds, static dbuf, XOR-swizzle). Lane owns ONE q-row; softmax
// in-lane (max3 chains); PV B-frag via cvt_pk + permlane32_swap (T12).
__global__ __launch_bounds__(256)
void attn_kernel(const ushort_t* __restrict__ q, const ushort_t* __restrict__ k,
                 const ushort_t* __restrict__ vt, const float* __restrict__ nkv,
                 ushort_t* __restrict__ out)
{
    __shared__ ushort_t kvs[2][8192];   // 2 x 16 KB (K tile 8 KB + V tile 8 KB)

    const int tid = threadIdx.x;
    const int w = tid >> 6, l = tid & 63;
    const int qc = l & 31, hh = l >> 5;            // lane's q-column, half
    const int bh = blockIdx.x, qb = blockIdx.y, hd = bh & 15;

    const ushort_t* kb = k  + (size_t)bh * 2048 * 64;
    const ushort_t* vb = vt + (size_t)bh * 64 * 2048;

    // staging: LDS slot (row, s) holds logical granule s ^ (row&7);
    // thread handles granules tid and tid+256 of each tile (256-thr block).
    const int srow = tid >> 3;                         // 0..31
    const int ssl  = (tid & 7) ^ (srow & 7);
    const ushort_t* ksrc0 = kb + srow * 64 + ssl * 8;          // + t*4096
    const ushort_t* vsrc0 = vb + srow * 2048 + ssl * 8;        // + t*64
    const ushort_t* ksrc1 = ksrc0 + 32 * 64;                   // rows 32..63
    const ushort_t* vsrc1 = vsrc0 + 32 * 2048;

#define ATTN_STAGE(BUF, T)                                                              \
    do {                                                                                \
        __builtin_amdgcn_global_load_lds((gvoid_t*)(ksrc0 + (T) * 4096),                \
            (svoid_t*)(&kvs[BUF][tid * 8]), 16, 0, 0);                                  \
        __builtin_amdgcn_global_load_lds((gvoid_t*)(ksrc1 + (T) * 4096),                \
            (svoid_t*)(&kvs[BUF][(tid + 256) * 8]), 16, 0, 0);                          \
        __builtin_amdgcn_global_load_lds((gvoid_t*)(vsrc0 + (T) * 64),                  \
            (svoid_t*)(&kvs[BUF][4096 + tid * 8]), 16, 0, 0);                           \
        __builtin_amdgcn_global_load_lds((gvoid_t*)(vsrc1 + (T) * 64),                  \
            (svoid_t*)(&kvs[BUF][4096 + (tid + 256) * 8]), 16, 0, 0);                   \
    } while (0)

    // Q: lane holds Q[q = qb*128 + w*32 + qc][d = dwin*16 + 8*hh + i] (prescaled)
    const ushort_t* qbase = q + ((size_t)bh * 2048 + qb * 128 + w * 32 + qc) * 64;
    Frag aq[4];
    #pragma unroll
    for (int dwin = 0; dwin < 4; ++dwin)
        aq[dwin].u4 = *reinterpret_cast<const uint4*>(qbase + dwin * 16 + hh * 8);

    // snull = q_row . null_k  (lane holds 32 of 64 dims; reduce across halves)
    float snull = 0.f;
    #pragma unroll
    for (int dwin = 0; dwin < 4; ++dwin) {
        const float4 n0 = *reinterpret_cast<const float4*>(nkv + hd * 64 + dwin * 16 + hh * 8);
        const float4 n1 = *reinterpret_cast<const float4*>(nkv + hd * 64 + dwin * 16 + hh * 8 + 4);
        snull += bf2f(aq[dwin].s[0]) * n0.x + bf2f(aq[dwin].s[1]) * n0.y
               + bf2f(aq[dwin].s[2]) * n0.z + bf2f(aq[dwin].s[3]) * n0.w;
        snull += bf2f(aq[dwin].s[4]) * n1.x + bf2f(aq[dwin].s[5]) * n1.y
               + bf2f(aq[dwin].s[6]) * n1.z + bf2f(aq[dwin].s[7]) * n1.w;
    }
    snull += __shfl_xor(snull, 32);

    float m_run  = snull;
    float l_part = (hh == 0) ? 1.f : 0.f;

    // acc[db] = O^T block: lane holds O[q=qc][d = db*32 + (r&3) + 8*(r>>2) + 4*hh]
    f32x16 acc[2];
    #pragma unroll
    for (int db = 0; db < 2; ++db)
        #pragma unroll
        for (int r = 0; r < 16; ++r)
            acc[db][r] = nkv[1024 + hd * 64 + db * 32 + (r & 3) + 8 * (r >> 2) + 4 * hh];

    const int swz = l & 7;

#define ATTN_PROC(BUF)                                                                  \
    do {                                                                                \
        const ushort_t* kbuf = &kvs[BUF][0];                                            \
        const ushort_t* vbuf = &kvs[BUF][4096];                                         \
        f32x16 st[2];                                                                   \
        __builtin_amdgcn_s_setprio(1);                                                  \
        _Pragma("unroll")                                                               \
        for (int kvblk = 0; kvblk < 2; ++kvblk) {                                       \
            f32x16 z = {0.f,0.f,0.f,0.f,0.f,0.f,0.f,0.f,                                \
                        0.f,0.f,0.f,0.f,0.f,0.f,0.f,0.f};                               \
            _Pragma("unroll")                                                           \
            for (int dwin = 0; dwin < 4; ++dwin) {                                      \
                Frag kf;                                                                \
                kf.u4 = *reinterpret_cast<const uint4*>(                                \
                    &kbuf[(kvblk * 32 + qc) * 64 + (((dwin << 1) | hh) ^ swz) * 8]);    \
                z = mfma32(kf.b, aq[dwin].b, z);                                        \
            }                                                                           \
            st[kvblk] = z;                                                              \
        }                                                                               \
        __builtin_amdgcn_s_setprio(0);                                                  \
        float ch[4];                                                                    \
        _Pragma("unroll")                                                               \
        for (int j = 0; j < 4; ++j) {                                                   \
            const int B = j >> 1, base = (j & 1) * 8;                                   \
            ch[j] = fmaxf(st[B][base], st[B][base + 1]);                                \
            ch[j] = fmax3(ch[j], st[B][base + 2], st[B][base + 3]);                     \
            ch[j] = fmax3(ch[j], st[B][base + 4], st[B][base + 5]);                     \
            ch[j] = fmax3(ch[j], st[B][base + 6], st[B][base + 7]);                     \
        }                                                                               \
        float pm = fmaxf(fmax3(ch[0], ch[1], ch[2]), ch[3]);                            \
        pm = fmaxf(pm, __shfl_xor(pm, 32));                                             \
        if (__any(pm > m_run + 12.f)) {                                                 \
            const float nm = fmaxf(m_run, pm);                                          \
            const float alpha = exp2_fast(m_run - nm);                                  \
            m_run = nm;                                                                 \
            l_part *= alpha;                                                            \
            _Pragma("unroll")                                                           \
            for (int db = 0; db < 2; ++db)                                              \
                _Pragma("unroll")                                                       \
                for (int r = 0; r < 16; ++r)                                            \
                    acc[db][r] *= alpha;                                                \
        }                                                                               \
        float ts = 0.f;                                                                 \
        _Pragma("unroll")                                                               \
        for (int B = 0; B < 2; ++B)                                                     \
            _Pragma("unroll")                                                           \
            for (int r = 0; r < 16; ++r) {                                              \
                st[B][r] = exp2_fast(st[B][r] - m_run);                                 \
                ts += st[B][r];                                                         \
            }                                                                           \
        l_part += ts;                                                                   \
        Frag pb[2][2];                                                                  \
        _Pragma("unroll")                                                               \
        for (int B = 0; B < 2; ++B)                                                     \
            _Pragma("unroll")                                                           \
            for (int kbv = 0; kbv < 2; ++kbv) {                                         \
                unsigned P = pack2bf(st[B][8 * kbv + 0], st[B][8 * kbv + 1]);           \
                unsigned Q = pack2bf(st[B][8 * kbv + 2], st[B][8 * kbv + 3]);           \
                unsigned R = pack2bf(st[B][8 * kbv + 4], st[B][8 * kbv + 5]);           \
                unsigned S = pack2bf(st[B][8 * kbv + 6], st[B][8 * kbv + 7]);           \
                pl32swap(P, R);                                                         \
                pl32swap(Q, S);                                                         \
                pb[B][kbv].u4.x = P;                                                    \
                pb[B][kbv].u4.y = Q;                                                    \
                pb[B][kbv].u4.z = R;                                                    \
                pb[B][kbv].u4.w = S;                                                    \
            }                                                                           \
        __builtin_amdgcn_s_setprio(1);                                                  \
        _Pragma("unroll")                                                               \
        for (int db = 0; db < 2; ++db)                                                  \
            _Pragma("unroll")                                                           \
            for (int B = 0; B < 2; ++B)                                                 \
                _Pragma("unroll")                                                       \
                for (int kbv = 0; kbv < 2; ++kbv) {                                     \
                    Frag vf;                                                            \
                    vf.u4 = *reinterpret_cast<const uint4*>(                            \
                        &vbuf[(db * 32 + qc) * 64 +                                     \
                              (((B << 2) | (kbv << 1) | hh) ^ swz) * 8]);               \
                    acc[db] = mfma32(vf.b, pb[B][kbv].b, acc[db]);                      \
                }                                                                       \
        __builtin_amdgcn_s_setprio(0);                                                  \
    } while (0)

    ATTN_STAGE(0, 0);
    #pragma unroll 1
    for (int tt = 0; tt < 16; ++tt) {
        __syncthreads();                       // stage(2tt) landed; prev buf0 reads done
        ATTN_STAGE(1, 2 * tt + 1);
        ATTN_PROC(0);
        __syncthreads();                       // stage(2tt+1) landed; buf1 reads done
        if (tt < 15) ATTN_STAGE(0, 2 * tt + 2);
        ATTN_PROC(1);
    }

    // final l across halves; normalize per-lane
    l_part += __shfl_xor(l_part, 32);
    const float inv = 1.f / l_part;

    // epilogue: transpose O through LDS (kvs[0] free, 16 KB) for coalesced stores
    __syncthreads();
    ushort_t* olds = &kvs[0][0];    // [128 rows][8 granules 16B], swizzled
    const int rowq = w * 32 + qc;
    #pragma unroll
    for (int db = 0; db < 2; ++db)
        #pragma unroll
        for (int rq = 0; rq < 4; ++rq) {
            uint2 ov;
            ov.x = pack2bf(acc[db][4 * rq + 0] * inv, acc[db][4 * rq + 1] * inv);
            ov.y = pack2bf(acc[db][4 * rq + 2] * inv, acc[db][4 * rq + 3] * inv);
            const int gL = db * 4 + rq;                     // d granule (8 ush)
            const int phys = gL ^ (qc & 7);
            *reinterpret_cast<uint2*>(&olds[(rowq * 8 + phys) * 8 + 4 * hh]) = ov;
        }
    __syncthreads();

    const size_t obase = ((size_t)(bh >> 4) * 2048 + qb * 128) * 1024 + hd * 64;
    #pragma unroll
    for (int p = 0; p < 4; ++p) {
        const int G = p * 256 + tid;
        const int row = G >> 3, sl = G & 7;
        const int phys = sl ^ (row & 7);
        uint4 v = *reinterpret_cast<const uint4*>(&olds[(row * 8 + phys) * 8]);
        *reinterpret_cast<uint4*>(out + obase + (size_t)row * 1024 + sl * 8) = v;
    }
#undef ATTN_STAGE
#undef ATTN_PROC
}

// ---------------------------------------------------------------- launch
extern "C" void kernel_launch(void* const* d_in, const int* in_sizes, int n_in,
                              void* d_out, int out_size, void* d_ws, size_t ws_size,
                              hipStream_t stream)
{
    (void)in_sizes; (void)n_in; (void)out_size; (void)ws_size;
    const float* x     = (const float*)d_in[0];
    const float* gamma = (const float*)d_in[1];
    const float* w_q   = (const float*)d_in[2];
    const float* w_kv  = (const float*)d_in[3];
    const float* w_out = (const float*)d_in[4];
    const float* nkv   = (const float*)d_in[5];
    float* out = (float*)d_out;

    char* ws = (char*)d_ws;
    ushort_t* xn    = (ushort_t*)(ws);               // 16 MB  [8192,1024] bf16
    ushort_t* wqkvT = (ushort_t*)(ws + 16777216);    //  6 MB  [3072,1024] (q|k|v)
    ushort_t* woT   = (ushort_t*)(ws + 23068672);    //  2 MB  [1024,1024]
    ushort_t* qh    = (ushort_t*)(ws + 25165824);    // 16 MB  [b,h,2048,64]  (kh = qh+8388608)
    ushort_t* vtb   = (ushort_t*)(ws + 58720256);    // 16 MB  [b,h,64,2048]
    ushort_t* ao    = xn;                            // attn output reuses xn
    ushort_t* kh    = qh + 8388608;

    ln_kernel<<<dim3(8192), dim3(256), 0, stream>>>(x, gamma, xn);
    wt_kernel<<<dim3(32, 32), dim3(32, 8), 0, stream>>>(w_q,  wqkvT, 1024, 1024);
    wt_kernel<<<dim3(64, 32), dim3(32, 8), 0, stream>>>(w_kv, wqkvT + 1048576, 1024, 2048);
    wt_kernel<<<dim3(32, 32), dim3(32, 8), 0, stream>>>(w_out, woT, 1024, 1024);

    // fused QKV projection: N = 3072
    gemm_kernel<0><<<dim3(64, 24), dim3(256), 0, stream>>>(xn, wqkvT, qh, vtb, nullptr);

    attn_kernel<<<dim3(64, 16), dim3(256), 0, stream>>>(qh, kh, vtb, nkv, ao);

    gemm_kernel<2><<<dim3(64, 8), dim3(256), 0, stream>>>(ao, woT, nullptr, nullptr, out);
}

// Round 8
// 209.363 us; speedup vs baseline: 1.0734x; 1.0734x over previous
//
#include <hip/hip_runtime.h>

typedef unsigned short ushort_t;
using f32x4   = __attribute__((ext_vector_type(4))) float;
using f32x16  = __attribute__((ext_vector_type(16))) float;
using bf16x8  = __attribute__((ext_vector_type(8))) __bf16;

typedef __attribute__((address_space(1))) const void gvoid_t;
typedef __attribute__((address_space(3))) void svoid_t;

union Frag {
    uint4    u4;
    bf16x8   b;
    ushort_t s[8];
};

__device__ __forceinline__ ushort_t f2bf(float f) {
    union { float f; unsigned u; } a; a.f = f;
    unsigned u = a.u;
    unsigned r = (u + 0x7fffu + ((u >> 16) & 1u)) >> 16;   // RNE
    return (ushort_t)r;
}
__device__ __forceinline__ float bf2f(ushort_t b) {
    union { unsigned u; float f; } a; a.u = ((unsigned)b) << 16;
    return a.f;
}
__device__ __forceinline__ unsigned pack2bf(float lo, float hi) {
    union { __bf16 h[2]; unsigned u; } p;
    p.h[0] = (__bf16)lo;
    p.h[1] = (__bf16)hi;
    return p.u;
}
__device__ __forceinline__ float exp2_fast(float x) {
#if __has_builtin(__builtin_amdgcn_exp2f)
    return __builtin_amdgcn_exp2f(x);
#else
    return exp2f(x);
#endif
}
__device__ __forceinline__ float fmax3(float a, float b, float c) {
    return fmaxf(fmaxf(a, b), c);     // clang fuses to v_max3_f32
}
// v_permlane32_swap_b32: x' = [x.lo, y.lo], y' = [x.hi, y.hi]
__device__ __forceinline__ void pl32swap(unsigned &x, unsigned &y) {
#if __has_builtin(__builtin_amdgcn_permlane32_swap)
    auto r = __builtin_amdgcn_permlane32_swap((int)x, (int)y, false, false);
    x = (unsigned)r[0]; y = (unsigned)r[1];
#else
    asm volatile("v_permlane32_swap_b32 %0, %1" : "+v"(x), "+v"(y));
#endif
}
__device__ __forceinline__ f32x16 mfma32(bf16x8 a, bf16x8 b, f32x16 c) {
    return __builtin_amdgcn_mfma_f32_32x32x16_bf16(a, b, c, 0, 0, 0);
}

// LOG2E folded into q-prescale so softmax runs in exp2 domain
#define QSCALE 0.18033688011112042f   // 0.125 * log2(e)

// ---------------------------------------------------------------- LayerNorm
__global__ __launch_bounds__(256)
void ln_kernel(const float* __restrict__ x, const float* __restrict__ gamma,
               ushort_t* __restrict__ xn)
{
    const int row = blockIdx.x;
    const int tid = threadIdx.x;
    const float4 v = *reinterpret_cast<const float4*>(x + (size_t)row * 1024 + tid * 4);

    float s = v.x + v.y + v.z + v.w;
    float q = v.x * v.x + v.y * v.y + v.z * v.z + v.w * v.w;
    #pragma unroll
    for (int off = 1; off <= 32; off <<= 1) {
        s += __shfl_xor(s, off);
        q += __shfl_xor(q, off);
    }
    __shared__ float ss[4], sq[4];
    if ((tid & 63) == 0) { ss[tid >> 6] = s; sq[tid >> 6] = q; }
    __syncthreads();
    const float S  = ss[0] + ss[1] + ss[2] + ss[3];
    const float Q  = sq[0] + sq[1] + sq[2] + sq[3];
    const float mu = S * (1.0f / 1024.0f);
    const float var = Q * (1.0f / 1024.0f) - mu * mu;
    const float rstd = rsqrtf(var + 1e-5f);

    const float4 gm = *reinterpret_cast<const float4*>(gamma + tid * 4);
    ushort4 o;
    o.x = f2bf((v.x - mu) * rstd * gm.x);
    o.y = f2bf((v.y - mu) * rstd * gm.y);
    o.z = f2bf((v.z - mu) * rstd * gm.z);
    o.w = f2bf((v.w - mu) * rstd * gm.w);
    *reinterpret_cast<ushort4*>(xn + (size_t)row * 1024 + tid * 4) = o;
}

// ------------------------------------------- weight transpose fp32[K][N] -> bf16[N][K]
__global__ __launch_bounds__(256)
void wt_kernel(const float* __restrict__ w, ushort_t* __restrict__ wt, int K, int N)
{
    __shared__ float tile[32][33];
    const int n0 = blockIdx.x * 32, k0 = blockIdx.y * 32;
    const int tx = threadIdx.x, ty = threadIdx.y;   // (32, 8)
    #pragma unroll
    for (int i = 0; i < 4; ++i) {
        int r = ty + i * 8;
        tile[r][tx] = w[(size_t)(k0 + r) * N + n0 + tx];
    }
    __syncthreads();
    #pragma unroll
    for (int i = 0; i < 4; ++i) {
        int r = ty + i * 8;
        wt[(size_t)(n0 + r) * K + k0 + tx] = f2bf(tile[tx][r]);
    }
}

// ---------------------------------------------------------------- GEMM v3 (dbuf)
__device__ __forceinline__ void gemm_stage(const ushort_t* const* asrc,
                                           const ushort_t* const* bsrc,
                                           ushort_t* dA, ushort_t* dB,
                                           int kt, int tid)
{
    #pragma unroll
    for (int j = 0; j < 4; ++j) {
        __builtin_amdgcn_global_load_lds((gvoid_t*)(asrc[j] + kt * 64),
                                         (svoid_t*)(&dA[(j * 256 + tid) * 8]), 16, 0, 0);
        __builtin_amdgcn_global_load_lds((gvoid_t*)(bsrc[j] + kt * 64),
                                         (svoid_t*)(&dB[(j * 256 + tid) * 8]), 16, 0, 0);
    }
}
__device__ __forceinline__ void gemm_comp(const ushort_t* bA, const ushort_t* bB,
                                          f32x4 (&acc)[4][4],
                                          int wm, int wn, int g, int c, int swz)
{
    #pragma unroll
    for (int kk = 0; kk < 2; ++kk) {
        Frag af[4], bfr[4];
        #pragma unroll
        for (int mi = 0; mi < 4; ++mi)
            af[mi].u4 = *reinterpret_cast<const uint4*>(
                &bA[(wm * 64 + mi * 16 + c) * 64 + ((((kk << 2) | g)) ^ swz) * 8]);
        #pragma unroll
        for (int ni = 0; ni < 4; ++ni)
            bfr[ni].u4 = *reinterpret_cast<const uint4*>(
                &bB[(wn * 64 + ni * 16 + c) * 64 + ((((kk << 2) | g)) ^ swz) * 8]);
        #pragma unroll
        for (int mi = 0; mi < 4; ++mi)
            #pragma unroll
            for (int ni = 0; ni < 4; ++ni)
                acc[mi][ni] = __builtin_amdgcn_mfma_f32_16x16x32_bf16(
                    af[mi].b, bfr[ni].b, acc[mi][ni], 0, 0, 0);
    }
}

template<int MODE>
__global__ __launch_bounds__(256)
void gemm_kernel(const ushort_t* __restrict__ A, const ushort_t* __restrict__ Bt,
                 ushort_t* __restrict__ o16a, ushort_t* __restrict__ o16b,
                 float* __restrict__ o32)
{
    __shared__ ushort_t ldsA[2][128 * 64];   // 2 x 16 KB
    __shared__ ushort_t ldsB[2][128 * 64];

    const int tid = threadIdx.x;
    const int m0 = blockIdx.x * 128, n0 = blockIdx.y * 128;
    const int w = tid >> 6, l = tid & 63, g = l >> 4, c = l & 15;
    const int wm = w >> 1, wn = w & 1;

    const ushort_t* asrc[4];
    const ushort_t* bsrc[4];
    #pragma unroll
    for (int j = 0; j < 4; ++j) {
        const int gidx = j * 256 + tid;
        const int row = gidx >> 3;
        const int sl  = (gidx & 7) ^ (row & 7);
        asrc[j] = A  + (size_t)(m0 + row) * 1024 + sl * 8;
        bsrc[j] = Bt + (size_t)(n0 + row) * 1024 + sl * 8;
    }

    f32x4 acc[4][4];
    #pragma unroll
    for (int mi = 0; mi < 4; ++mi)
        #pragma unroll
        for (int ni = 0; ni < 4; ++ni)
            acc[mi][ni] = (f32x4){0.f, 0.f, 0.f, 0.f};

    const int swz = c & 7;

    gemm_stage(asrc, bsrc, ldsA[0], ldsB[0], 0, tid);
    #pragma unroll 1
    for (int k2 = 0; k2 < 8; ++k2) {
        __syncthreads();
        gemm_stage(asrc, bsrc, ldsA[1], ldsB[1], 2 * k2 + 1, tid);
        gemm_comp(ldsA[0], ldsB[0], acc, wm, wn, g, c, swz);
        __syncthreads();
        if (k2 < 7) gemm_stage(asrc, bsrc, ldsA[0], ldsB[0], 2 * k2 + 2, tid);
        gemm_comp(ldsA[1], ldsB[1], acc, wm, wn, g, c, swz);
    }

    #pragma unroll
    for (int mi = 0; mi < 4; ++mi) {
        const int mbase = m0 + wm * 64 + mi * 16 + g * 4;
        #pragma unroll
        for (int ni = 0; ni < 4; ++ni) {
            const int n = n0 + wn * 64 + ni * 16 + c;
            if (MODE == 0) {
                if (n < 2048) {                 // q (scaled) or k
                    const int nn = n & 1023;
                    const int hh = nn >> 6, d = nn & 63;
                    const size_t base = (n < 1024) ? 0 : 8388608;
                    const float scale = (n < 1024) ? QSCALE : 1.f;
                    #pragma unroll
                    for (int r = 0; r < 4; ++r) {
                        const int m = mbase + r;
                        const int b = m >> 11, tok = m & 2047;
                        o16a[base + (((size_t)b * 16 + hh) * 2048 + tok) * 64 + d] =
                            f2bf(acc[mi][ni][r] * scale);
                    }
                } else {                        // v, transposed store
                    const int nn = n - 2048;
                    const int hh = nn >> 6, d = nn & 63;
                    const int b = mbase >> 11, tok0 = mbase & 2047;
                    ushort4 pv;
                    pv.x = f2bf(acc[mi][ni][0]);
                    pv.y = f2bf(acc[mi][ni][1]);
                    pv.z = f2bf(acc[mi][ni][2]);
                    pv.w = f2bf(acc[mi][ni][3]);
                    *reinterpret_cast<ushort4*>(
                        o16b + (((size_t)b * 16 + hh) * 64 + d) * 2048 + tok0) = pv;
                }
            } else {
                #pragma unroll
                for (int r = 0; r < 4; ++r)
                    o32[(size_t)(mbase + r) * 1024 + n] = acc[mi][ni][r];
            }
        }
    }
}

// ---------------------------------------------------------------- flash attention v8
// 32x32x16 MFMA; wave owns 64 q-rows (2 q-blocks of 32) -> K/V LDS reads shared
// across both q-blocks (per-q LDS traffic halved vs v6). 8 waves x 64 q = 512
// q/block; grid (64 bh, 4 qb) = 256 blocks = 1/CU, 32/XCD (bh-pinned).
// K/V LDS-staged (global_load_lds, dbuf, XOR-swizzle). Softmax in-lane (max3),
// log2 domain, defer-max; PV B-frags via cvt_pk + permlane32_swap (T12).
__global__ __launch_bounds__(512)
void attn_kernel(const ushort_t* __restrict__ q, const ushort_t* __restrict__ k,
                 const ushort_t* __restrict__ vt, const float* __restrict__ nkv,
                 ushort_t* __restrict__ out)
{
    __shared__ ushort_t kvs[2][8192];   // 2 x 16 KB (K tile 8 KB + V tile 8 KB)

    const int tid = threadIdx.x;
    const int w = tid >> 6, l = tid & 63;
    const int qc = l & 31, hh = l >> 5;
    const int bh = blockIdx.x, qb = blockIdx.y, hd = bh & 15;

    const ushort_t* kb = k  + (size_t)bh * 2048 * 64;
    const ushort_t* vb = vt + (size_t)bh * 64 * 2048;

    // staging: LDS slot (row, s) holds logical granule s ^ (row&7)
    const int srow = tid >> 3;                         // 0..63
    const int ssl  = (tid & 7) ^ (srow & 7);
    const ushort_t* ksrc = kb + srow * 64 + ssl * 8;   // + t*4096
    const ushort_t* vsrc = vb + srow * 2048 + ssl * 8; // + t*64

    // Q: aq[j][dwin] = Q[q = qb*512 + w*64 + j*32 + qc][d = dwin*16 + 8*hh + i]
    const ushort_t* qbase = q + ((size_t)bh * 2048 + qb * 512 + w * 64 + qc) * 64;
    Frag aq[2][4];
    #pragma unroll
    for (int j = 0; j < 2; ++j)
        #pragma unroll
        for (int dwin = 0; dwin < 4; ++dwin)
            aq[j][dwin].u4 = *reinterpret_cast<const uint4*>(
                qbase + j * 32 * 64 + dwin * 16 + hh * 8);

    // snull per q-block
    float m_run[2], l_part[2];
    #pragma unroll
    for (int j = 0; j < 2; ++j) {
        float sn = 0.f;
        #pragma unroll
        for (int dwin = 0; dwin < 4; ++dwin) {
            const float4 n0 = *reinterpret_cast<const float4*>(nkv + hd * 64 + dwin * 16 + hh * 8);
            const float4 n1 = *reinterpret_cast<const float4*>(nkv + hd * 64 + dwin * 16 + hh * 8 + 4);
            sn += bf2f(aq[j][dwin].s[0]) * n0.x + bf2f(aq[j][dwin].s[1]) * n0.y
                + bf2f(aq[j][dwin].s[2]) * n0.z + bf2f(aq[j][dwin].s[3]) * n0.w;
            sn += bf2f(aq[j][dwin].s[4]) * n1.x + bf2f(aq[j][dwin].s[5]) * n1.y
                + bf2f(aq[j][dwin].s[6]) * n1.z + bf2f(aq[j][dwin].s[7]) * n1.w;
        }
        sn += __shfl_xor(sn, 32);
        m_run[j]  = sn;
        l_part[j] = (hh == 0) ? 1.f : 0.f;
    }

    // acc[j][db] : lane holds O[q-block j, q=qc][d = db*32 + (r&3)+8*(r>>2)+4*hh]
    f32x16 acc[2][2];
    #pragma unroll
    for (int db = 0; db < 2; ++db) {
        f32x16 tmp;
        #pragma unroll
        for (int r = 0; r < 16; ++r)
            tmp[r] = nkv[1024 + hd * 64 + db * 32 + (r & 3) + 8 * (r >> 2) + 4 * hh];
        acc[0][db] = tmp;
        acc[1][db] = tmp;
    }

    const int swz = l & 7;

    __builtin_amdgcn_global_load_lds((gvoid_t*)(ksrc), (svoid_t*)(&kvs[0][tid * 8]), 16, 0, 0);
    __builtin_amdgcn_global_load_lds((gvoid_t*)(vsrc), (svoid_t*)(&kvs[0][4096 + tid * 8]), 16, 0, 0);
    __syncthreads();

    int cur = 0;
    #pragma unroll 1
    for (int t = 0; t < 32; ++t) {
        if (t < 31) {
            __builtin_amdgcn_global_load_lds((gvoid_t*)(ksrc + (t + 1) * 4096),
                                             (svoid_t*)(&kvs[cur ^ 1][tid * 8]), 16, 0, 0);
            __builtin_amdgcn_global_load_lds((gvoid_t*)(vsrc + (t + 1) * 64),
                                             (svoid_t*)(&kvs[cur ^ 1][4096 + tid * 8]), 16, 0, 0);
        }
        const ushort_t* kbuf = &kvs[cur][0];
        const ushort_t* vbuf = &kvs[cur][4096];

        // QK^T: one K-frag read serves BOTH q-blocks
        f32x16 st[2][2];
        #pragma unroll
        for (int j = 0; j < 2; ++j)
            #pragma unroll
            for (int kvblk = 0; kvblk < 2; ++kvblk)
                st[j][kvblk] = (f32x16){0.f,0.f,0.f,0.f,0.f,0.f,0.f,0.f,
                                        0.f,0.f,0.f,0.f,0.f,0.f,0.f,0.f};
        __builtin_amdgcn_s_setprio(1);
        #pragma unroll
        for (int kvblk = 0; kvblk < 2; ++kvblk)
            #pragma unroll
            for (int dwin = 0; dwin < 4; ++dwin) {
                Frag kf;
                kf.u4 = *reinterpret_cast<const uint4*>(
                    &kbuf[(kvblk * 32 + qc) * 64 + (((dwin << 1) | hh) ^ swz) * 8]);
                st[0][kvblk] = mfma32(kf.b, aq[0][dwin].b, st[0][kvblk]);
                st[1][kvblk] = mfma32(kf.b, aq[1][dwin].b, st[1][kvblk]);
            }
        __builtin_amdgcn_s_setprio(0);

        // softmax per q-block (in-lane, max3 chains)
        float pm[2];
        #pragma unroll
        for (int j = 0; j < 2; ++j) {
            float ch[4];
            #pragma unroll
            for (int jj = 0; jj < 4; ++jj) {
                const int B = jj >> 1, base = (jj & 1) * 8;
                ch[jj] = fmaxf(st[j][B][base], st[j][B][base + 1]);
                ch[jj] = fmax3(ch[jj], st[j][B][base + 2], st[j][B][base + 3]);
                ch[jj] = fmax3(ch[jj], st[j][B][base + 4], st[j][B][base + 5]);
                ch[jj] = fmax3(ch[jj], st[j][B][base + 6], st[j][B][base + 7]);
            }
            float pmv = fmaxf(fmax3(ch[0], ch[1], ch[2]), ch[3]);
            pmv = fmaxf(pmv, __shfl_xor(pmv, 32));
            pm[j] = pmv;
        }

        if (__any(fmaxf(pm[0] - m_run[0], pm[1] - m_run[1]) > 12.f)) {  // T13
            #pragma unroll
            for (int j = 0; j < 2; ++j) {
                const float nm = fmaxf(m_run[j], pm[j]);
                const float alpha = exp2_fast(m_run[j] - nm);
                m_run[j] = nm;
                l_part[j] *= alpha;
                #pragma unroll
                for (int db = 0; db < 2; ++db)
                    #pragma unroll
                    for (int r = 0; r < 16; ++r)
                        acc[j][db][r] *= alpha;
            }
        }

        Frag pb[2][2][2];
        #pragma unroll
        for (int j = 0; j < 2; ++j) {
            float ts = 0.f;
            #pragma unroll
            for (int B = 0; B < 2; ++B)
                #pragma unroll
                for (int r = 0; r < 16; ++r) {
                    st[j][B][r] = exp2_fast(st[j][B][r] - m_run[j]);
                    ts += st[j][B][r];
                }
            l_part[j] += ts;
            #pragma unroll
            for (int B = 0; B < 2; ++B)
                #pragma unroll
                for (int kbv = 0; kbv < 2; ++kbv) {
                    unsigned P = pack2bf(st[j][B][8 * kbv + 0], st[j][B][8 * kbv + 1]);
                    unsigned Q = pack2bf(st[j][B][8 * kbv + 2], st[j][B][8 * kbv + 3]);
                    unsigned R = pack2bf(st[j][B][8 * kbv + 4], st[j][B][8 * kbv + 5]);
                    unsigned S = pack2bf(st[j][B][8 * kbv + 6], st[j][B][8 * kbv + 7]);
                    pl32swap(P, R);
                    pl32swap(Q, S);
                    pb[j][B][kbv].u4.x = P;
                    pb[j][B][kbv].u4.y = Q;
                    pb[j][B][kbv].u4.z = R;
                    pb[j][B][kbv].u4.w = S;
                }
        }

        // PV: one V-frag read serves BOTH q-blocks
        __builtin_amdgcn_s_setprio(1);
        #pragma unroll
        for (int db = 0; db < 2; ++db)
            #pragma unroll
            for (int B = 0; B < 2; ++B)
                #pragma unroll
                for (int kbv = 0; kbv < 2; ++kbv) {
                    Frag vf;
                    vf.u4 = *reinterpret_cast<const uint4*>(
                        &vbuf[(db * 32 + qc) * 64 +
                              (((B << 2) | (kbv << 1) | hh) ^ swz) * 8]);
                    acc[0][db] = mfma32(vf.b, pb[0][B][kbv].b, acc[0][db]);
                    acc[1][db] = mfma32(vf.b, pb[1][B][kbv].b, acc[1][db]);
                }
        __builtin_amdgcn_s_setprio(0);

        __syncthreads();   // drains vmcnt (stage t+1); guards buffer swap
        cur ^= 1;
    }

    // finalize l; two-pass LDS transpose epilogue (256 rows = 32 KB per pass)
    float inv[2];
    #pragma unroll
    for (int j = 0; j < 2; ++j) {
        l_part[j] += __shfl_xor(l_part[j], 32);
        inv[j] = 1.f / l_part[j];
    }

    ushort_t* olds = &kvs[0][0];    // 32 KB scratch
    const size_t obase = ((size_t)(bh >> 4) * 2048) * 1024 + hd * 64;
    #pragma unroll
    for (int j = 0; j < 2; ++j) {
        __syncthreads();
        const int rowq = w * 32 + qc;          // local row 0..255
        #pragma unroll
        for (int db = 0; db < 2; ++db)
            #pragma unroll
            for (int rq = 0; rq < 4; ++rq) {
                uint2 ov;
                ov.x = pack2bf(acc[j][db][4 * rq + 0] * inv[j],
                               acc[j][db][4 * rq + 1] * inv[j]);
                ov.y = pack2bf(acc[j][db][4 * rq + 2] * inv[j],
                               acc[j][db][4 * rq + 3] * inv[j]);
                const int gL = db * 4 + rq;
                const int phys = gL ^ (qc & 7);
                *reinterpret_cast<uint2*>(&olds[(rowq * 8 + phys) * 8 + 4 * hh]) = ov;
            }
        __syncthreads();
        #pragma unroll
        for (int p = 0; p < 4; ++p) {
            const int G = p * 512 + tid;       // 2048 granules = 256 rows x 8
            const int row = G >> 3, sl = G & 7;
            const int phys = sl ^ (row & 7);
            uint4 v = *reinterpret_cast<const uint4*>(&olds[(row * 8 + phys) * 8]);
            const int gr = qb * 512 + (row >> 5) * 64 + j * 32 + (row & 31);
            *reinterpret_cast<uint4*>(out + obase + (size_t)gr * 1024 + sl * 8) = v;
        }
    }
}

// ---------------------------------------------------------------- launch
extern "C" void kernel_launch(void* const* d_in, const int* in_sizes, int n_in,
                              void* d_out, int out_size, void* d_ws, size_t ws_size,
                              hipStream_t stream)
{
    (void)in_sizes; (void)n_in; (void)out_size; (void)ws_size;
    const float* x     = (const float*)d_in[0];
    const float* gamma = (const float*)d_in[1];
    const float* w_q   = (const float*)d_in[2];
    const float* w_kv  = (const float*)d_in[3];
    const float* w_out = (const float*)d_in[4];
    const float* nkv   = (const float*)d_in[5];
    float* out = (float*)d_out;

    char* ws = (char*)d_ws;
    ushort_t* xn    = (ushort_t*)(ws);               // 16 MB  [8192,1024] bf16
    ushort_t* wqkvT = (ushort_t*)(ws + 16777216);    //  6 MB  [3072,1024] (q|k|v)
    ushort_t* woT   = (ushort_t*)(ws + 23068672);    //  2 MB  [1024,1024]
    ushort_t* qh    = (ushort_t*)(ws + 25165824);    // 16 MB  [b,h,2048,64] (kh follows)
    ushort_t* vtb   = (ushort_t*)(ws + 58720256);    // 16 MB  [b,h,64,2048]
    ushort_t* ao    = xn;                            // attn output reuses xn
    ushort_t* kh    = qh + 8388608;

    ln_kernel<<<dim3(8192), dim3(256), 0, stream>>>(x, gamma, xn);
    wt_kernel<<<dim3(32, 32), dim3(32, 8), 0, stream>>>(w_q,  wqkvT, 1024, 1024);
    wt_kernel<<<dim3(64, 32), dim3(32, 8), 0, stream>>>(w_kv, wqkvT + 1048576, 1024, 2048);
    wt_kernel<<<dim3(32, 32), dim3(32, 8), 0, stream>>>(w_out, woT, 1024, 1024);

    // fused QKV projection: N = 3072
    gemm_kernel<0><<<dim3(64, 24), dim3(256), 0, stream>>>(xn, wqkvT, qh, vtb, nullptr);

    attn_kernel<<<dim3(64, 4), dim3(512), 0, stream>>>(qh, kh, vtb, nkv, ao);

    gemm_kernel<2><<<dim3(64, 8), dim3(256), 0, stream>>>(ao, woT, nullptr, nullptr, out);
}

// Round 11
// 208.069 us; speedup vs baseline: 1.0801x; 1.0062x over previous
//
#include <hip/hip_runtime.h>

typedef unsigned short ushort_t;
using f32x4   = __attribute__((ext_vector_type(4))) float;
using f32x16  = __attribute__((ext_vector_type(16))) float;
using bf16x8  = __attribute__((ext_vector_type(8))) __bf16;

typedef __attribute__((address_space(1))) const void gvoid_t;
typedef __attribute__((address_space(3))) void svoid_t;

union Frag {
    uint4    u4;
    bf16x8   b;
    ushort_t s[8];
};

__device__ __forceinline__ ushort_t f2bf(float f) {
    union { float f; unsigned u; } a; a.f = f;
    unsigned u = a.u;
    unsigned r = (u + 0x7fffu + ((u >> 16) & 1u)) >> 16;   // RNE
    return (ushort_t)r;
}
__device__ __forceinline__ float bf2f(ushort_t b) {
    union { unsigned u; float f; } a; a.u = ((unsigned)b) << 16;
    return a.f;
}
__device__ __forceinline__ unsigned pack2bf(float lo, float hi) {
    union { __bf16 h[2]; unsigned u; } p;
    p.h[0] = (__bf16)lo;
    p.h[1] = (__bf16)hi;
    return p.u;
}
__device__ __forceinline__ float exp2_fast(float x) {
#if __has_builtin(__builtin_amdgcn_exp2f)
    return __builtin_amdgcn_exp2f(x);
#else
    return exp2f(x);
#endif
}
// v_permlane32_swap_b32: x' = [x.lo, y.lo], y' = [x.hi, y.hi]
__device__ __forceinline__ void pl32swap(unsigned &x, unsigned &y) {
#if __has_builtin(__builtin_amdgcn_permlane32_swap)
    auto r = __builtin_amdgcn_permlane32_swap((int)x, (int)y, false, false);
    x = (unsigned)r[0]; y = (unsigned)r[1];
#else
    asm volatile("v_permlane32_swap_b32 %0, %1" : "+v"(x), "+v"(y));
#endif
}
__device__ __forceinline__ f32x16 mfma32(bf16x8 a, bf16x8 b, f32x16 c) {
    return __builtin_amdgcn_mfma_f32_32x32x16_bf16(a, b, c, 0, 0, 0);
}

// LOG2E folded into q-prescale so softmax runs in exp2 domain
#define QSCALE 0.18033688011112042f   // 0.125 * log2(e)

// ---------------------------------------------------------------- LayerNorm
__global__ __launch_bounds__(256)
void ln_kernel(const float* __restrict__ x, const float* __restrict__ gamma,
               ushort_t* __restrict__ xn)
{
    const int row = blockIdx.x;
    const int tid = threadIdx.x;
    const float4 v = *reinterpret_cast<const float4*>(x + (size_t)row * 1024 + tid * 4);

    float s = v.x + v.y + v.z + v.w;
    float q = v.x * v.x + v.y * v.y + v.z * v.z + v.w * v.w;
    #pragma unroll
    for (int off = 1; off <= 32; off <<= 1) {
        s += __shfl_xor(s, off);
        q += __shfl_xor(q, off);
    }
    __shared__ float ss[4], sq[4];
    if ((tid & 63) == 0) { ss[tid >> 6] = s; sq[tid >> 6] = q; }
    __syncthreads();
    const float S  = ss[0] + ss[1] + ss[2] + ss[3];
    const float Q  = sq[0] + sq[1] + sq[2] + sq[3];
    const float mu = S * (1.0f / 1024.0f);
    const float var = Q * (1.0f / 1024.0f) - mu * mu;
    const float rstd = rsqrtf(var + 1e-5f);

    const float4 gm = *reinterpret_cast<const float4*>(gamma + tid * 4);
    ushort4 o;
    o.x = f2bf((v.x - mu) * rstd * gm.x);
    o.y = f2bf((v.y - mu) * rstd * gm.y);
    o.z = f2bf((v.z - mu) * rstd * gm.z);
    o.w = f2bf((v.w - mu) * rstd * gm.w);
    *reinterpret_cast<ushort4*>(xn + (size_t)row * 1024 + tid * 4) = o;
}

// ------------------------------------------- weight transpose fp32[K][N] -> bf16[N][K]
__global__ __launch_bounds__(256)
void wt_kernel(const float* __restrict__ w, ushort_t* __restrict__ wt, int K, int N)
{
    __shared__ float tile[32][33];
    const int n0 = blockIdx.x * 32, k0 = blockIdx.y * 32;
    const int tx = threadIdx.x, ty = threadIdx.y;   // (32, 8)
    #pragma unroll
    for (int i = 0; i < 4; ++i) {
        int r = ty + i * 8;
        tile[r][tx] = w[(size_t)(k0 + r) * N + n0 + tx];
    }
    __syncthreads();
    #pragma unroll
    for (int i = 0; i < 4; ++i) {
        int r = ty + i * 8;
        wt[(size_t)(n0 + r) * K + k0 + tx] = f2bf(tile[tx][r]);
    }
}

// ---------------------------------------------------------------- GEMM v3 (dbuf)
__device__ __forceinline__ void gemm_stage(const ushort_t* const* asrc,
                                           const ushort_t* const* bsrc,
                                           ushort_t* dA, ushort_t* dB,
                                           int kt, int tid)
{
    #pragma unroll
    for (int j = 0; j < 4; ++j) {
        __builtin_amdgcn_global_load_lds((gvoid_t*)(asrc[j] + kt * 64),
                                         (svoid_t*)(&dA[(j * 256 + tid) * 8]), 16, 0, 0);
        __builtin_amdgcn_global_load_lds((gvoid_t*)(bsrc[j] + kt * 64),
                                         (svoid_t*)(&dB[(j * 256 + tid) * 8]), 16, 0, 0);
    }
}
__device__ __forceinline__ void gemm_comp(const ushort_t* bA, const ushort_t* bB,
                                          f32x4 (&acc)[4][4],
                                          int wm, int wn, int g, int c, int swz)
{
    #pragma unroll
    for (int kk = 0; kk < 2; ++kk) {
        Frag af[4], bfr[4];
        #pragma unroll
        for (int mi = 0; mi < 4; ++mi)
            af[mi].u4 = *reinterpret_cast<const uint4*>(
                &bA[(wm * 64 + mi * 16 + c) * 64 + ((((kk << 2) | g)) ^ swz) * 8]);
        #pragma unroll
        for (int ni = 0; ni < 4; ++ni)
            bfr[ni].u4 = *reinterpret_cast<const uint4*>(
                &bB[(wn * 64 + ni * 16 + c) * 64 + ((((kk << 2) | g)) ^ swz) * 8]);
        #pragma unroll
        for (int mi = 0; mi < 4; ++mi)
            #pragma unroll
            for (int ni = 0; ni < 4; ++ni)
                acc[mi][ni] = __builtin_amdgcn_mfma_f32_16x16x32_bf16(
                    af[mi].b, bfr[ni].b, acc[mi][ni], 0, 0, 0);
    }
}

template<int MODE>
__global__ __launch_bounds__(256)
void gemm_kernel(const ushort_t* __restrict__ A, const ushort_t* __restrict__ Bt,
                 ushort_t* __restrict__ o16a, ushort_t* __restrict__ o16b,
                 float* __restrict__ o32)
{
    __shared__ ushort_t ldsA[2][128 * 64];   // 2 x 16 KB
    __shared__ ushort_t ldsB[2][128 * 64];

    const int tid = threadIdx.x;
    const int m0 = blockIdx.x * 128, n0 = blockIdx.y * 128;
    const int w = tid >> 6, l = tid & 63, g = l >> 4, c = l & 15;
    const int wm = w >> 1, wn = w & 1;

    const ushort_t* asrc[4];
    const ushort_t* bsrc[4];
    #pragma unroll
    for (int j = 0; j < 4; ++j) {
        const int gidx = j * 256 + tid;
        const int row = gidx >> 3;
        const int sl  = (gidx & 7) ^ (row & 7);
        asrc[j] = A  + (size_t)(m0 + row) * 1024 + sl * 8;
        bsrc[j] = Bt + (size_t)(n0 + row) * 1024 + sl * 8;
    }

    f32x4 acc[4][4];
    #pragma unroll
    for (int mi = 0; mi < 4; ++mi)
        #pragma unroll
        for (int ni = 0; ni < 4; ++ni)
            acc[mi][ni] = (f32x4){0.f, 0.f, 0.f, 0.f};

    const int swz = c & 7;

    gemm_stage(asrc, bsrc, ldsA[0], ldsB[0], 0, tid);
    #pragma unroll 1
    for (int k2 = 0; k2 < 8; ++k2) {
        __syncthreads();
        gemm_stage(asrc, bsrc, ldsA[1], ldsB[1], 2 * k2 + 1, tid);
        gemm_comp(ldsA[0], ldsB[0], acc, wm, wn, g, c, swz);
        __syncthreads();
        if (k2 < 7) gemm_stage(asrc, bsrc, ldsA[0], ldsB[0], 2 * k2 + 2, tid);
        gemm_comp(ldsA[1], ldsB[1], acc, wm, wn, g, c, swz);
    }

    #pragma unroll
    for (int mi = 0; mi < 4; ++mi) {
        const int mbase = m0 + wm * 64 + mi * 16 + g * 4;
        #pragma unroll
        for (int ni = 0; ni < 4; ++ni) {
            const int n = n0 + wn * 64 + ni * 16 + c;
            if (MODE == 0) {
                if (n < 2048) {                 // q (scaled) or k
                    const int nn = n & 1023;
                    const int hh = nn >> 6, d = nn & 63;
                    const size_t base = (n < 1024) ? 0 : 8388608;
                    const float scale = (n < 1024) ? QSCALE : 1.f;
                    #pragma unroll
                    for (int r = 0; r < 4; ++r) {
                        const int m = mbase + r;
                        const int b = m >> 11, tok = m & 2047;
                        o16a[base + (((size_t)b * 16 + hh) * 2048 + tok) * 64 + d] =
                            f2bf(acc[mi][ni][r] * scale);
                    }
                } else {                        // v, transposed store
                    const int nn = n - 2048;
                    const int hh = nn >> 6, d = nn & 63;
                    const int b = mbase >> 11, tok0 = mbase & 2047;
                    ushort4 pv;
                    pv.x = f2bf(acc[mi][ni][0]);
                    pv.y = f2bf(acc[mi][ni][1]);
                    pv.z = f2bf(acc[mi][ni][2]);
                    pv.w = f2bf(acc[mi][ni][3]);
                    *reinterpret_cast<ushort4*>(
                        o16b + (((size_t)b * 16 + hh) * 64 + d) * 2048 + tok0) = pv;
                }
            } else {
                #pragma unroll
                for (int r = 0; r < 4; ++r)
                    o32[(size_t)(mbase + r) * 1024 + n] = acc[mi][ni][r];
            }
        }
    }
}

// ---------------------------------------------------------------- flash attention (R6, proven)
// 32x32x16 MFMA structure. grid (64 bh, 8 qb); 8 waves x 32 q-rows = 256 q/block.
// Each lane owns ONE q-row (q = lane&31). K/V LDS-staged (global_load_lds, dbuf,
// XOR-swizzle), stage-then-compute-then-__syncthreads loop (replay-verified in R6).
// In-lane log2 softmax, defer-max; PV B-frags via cvt_pk + permlane32_swap.
__global__ __launch_bounds__(512)
void attn_kernel(const ushort_t* __restrict__ q, const ushort_t* __restrict__ k,
                 const ushort_t* __restrict__ vt, const float* __restrict__ nkv,
                 ushort_t* __restrict__ out)
{
    __shared__ ushort_t kvs[2][8192];   // 2 x 16 KB (K tile 8 KB + V tile 8 KB)

    const int tid = threadIdx.x;
    const int w = tid >> 6, l = tid & 63;
    const int qc = l & 31, hh = l >> 5;            // lane's q-column, half
    const int bh = blockIdx.x, qb = blockIdx.y, hd = bh & 15;

    const ushort_t* kb = k  + (size_t)bh * 2048 * 64;
    const ushort_t* vb = vt + (size_t)bh * 64 * 2048;

    // staging: LDS slot (row, s) holds logical granule s ^ (row&7)
    const int srow = tid >> 3;                         // 0..63
    const int ssl  = (tid & 7) ^ (srow & 7);
    const ushort_t* ksrc = kb + srow * 64 + ssl * 8;   // + t*4096
    const ushort_t* vsrc = vb + srow * 2048 + ssl * 8; // + t*64

    // Q: lane holds Q[q = qb*256 + w*32 + qc][d = dwin*16 + 8*hh + i] (prescaled)
    const ushort_t* qbase = q + ((size_t)bh * 2048 + qb * 256 + w * 32 + qc) * 64;
    Frag aq[4];
    #pragma unroll
    for (int dwin = 0; dwin < 4; ++dwin)
        aq[dwin].u4 = *reinterpret_cast<const uint4*>(qbase + dwin * 16 + hh * 8);

    // snull = q_row . null_k  (lane holds 32 of 64 dims; reduce across halves)
    float snull = 0.f;
    #pragma unroll
    for (int dwin = 0; dwin < 4; ++dwin) {
        const float4 n0 = *reinterpret_cast<const float4*>(nkv + hd * 64 + dwin * 16 + hh * 8);
        const float4 n1 = *reinterpret_cast<const float4*>(nkv + hd * 64 + dwin * 16 + hh * 8 + 4);
        snull += bf2f(aq[dwin].s[0]) * n0.x + bf2f(aq[dwin].s[1]) * n0.y
               + bf2f(aq[dwin].s[2]) * n0.z + bf2f(aq[dwin].s[3]) * n0.w;
        snull += bf2f(aq[dwin].s[4]) * n1.x + bf2f(aq[dwin].s[5]) * n1.y
               + bf2f(aq[dwin].s[6]) * n1.z + bf2f(aq[dwin].s[7]) * n1.w;
    }
    snull += __shfl_xor(snull, 32);

    float m_run  = snull;
    float l_part = (hh == 0) ? 1.f : 0.f;

    // acc[db] = O^T block: lane holds O[q=qc][d = db*32 + (r&3) + 8*(r>>2) + 4*hh]
    f32x16 acc[2];
    #pragma unroll
    for (int db = 0; db < 2; ++db)
        #pragma unroll
        for (int r = 0; r < 16; ++r)
            acc[db][r] = nkv[1024 + hd * 64 + db * 32 + (r & 3) + 8 * (r >> 2) + 4 * hh];

    const int swz = l & 7;

    __builtin_amdgcn_global_load_lds((gvoid_t*)(ksrc), (svoid_t*)(&kvs[0][tid * 8]), 16, 0, 0);
    __builtin_amdgcn_global_load_lds((gvoid_t*)(vsrc), (svoid_t*)(&kvs[0][4096 + tid * 8]), 16, 0, 0);
    __syncthreads();

    int cur = 0;
    for (int t = 0; t < 32; ++t) {
        if (t < 31) {
            __builtin_amdgcn_global_load_lds((gvoid_t*)(ksrc + (t + 1) * 4096),
                                             (svoid_t*)(&kvs[cur ^ 1][tid * 8]), 16, 0, 0);
            __builtin_amdgcn_global_load_lds((gvoid_t*)(vsrc + (t + 1) * 64),
                                             (svoid_t*)(&kvs[cur ^ 1][4096 + tid * 8]), 16, 0, 0);
        }
        const ushort_t* kbuf = &kvs[cur][0];
        const ushort_t* vbuf = &kvs[cur][4096];

        // QK^T: st[kvblk] = S^T[kv = kvblk*32 + (r&3)+8*(r>>2)+4*hh][q = qc]
        f32x16 st[2];
        __builtin_amdgcn_s_setprio(1);
        #pragma unroll
        for (int kvblk = 0; kvblk < 2; ++kvblk) {
            f32x16 z = {0.f,0.f,0.f,0.f, 0.f,0.f,0.f,0.f, 0.f,0.f,0.f,0.f, 0.f,0.f,0.f,0.f};
            #pragma unroll
            for (int dwin = 0; dwin < 4; ++dwin) {
                Frag kf;   // K[kv = kvblk*32 + (l&31)][d = dwin*16 + 8*hh + i]
                kf.u4 = *reinterpret_cast<const uint4*>(
                    &kbuf[(kvblk * 32 + (l & 31)) * 64 + (((dwin << 1) | hh) ^ swz) * 8]);
                z = mfma32(kf.b, aq[dwin].b, z);
            }
            st[kvblk] = z;
        }
        __builtin_amdgcn_s_setprio(0);

        // ---- softmax, fully in-lane for q-row qc ----
        float pm = st[0][0];
        #pragma unroll
        for (int r = 1; r < 16; ++r) pm = fmaxf(pm, st[0][r]);
        #pragma unroll
        for (int r = 0; r < 16; ++r) pm = fmaxf(pm, st[1][r]);
        pm = fmaxf(pm, __shfl_xor(pm, 32));

        if (__any(pm > m_run + 12.f)) {      // T13 defer-max (log2 units)
            const float nm = fmaxf(m_run, pm);
            const float alpha = exp2_fast(m_run - nm);
            m_run = nm;
            l_part *= alpha;
            #pragma unroll
            for (int db = 0; db < 2; ++db)
                #pragma unroll
                for (int r = 0; r < 16; ++r)
                    acc[db][r] *= alpha;     // per-lane scalar
        }

        float ts = 0.f;
        #pragma unroll
        for (int B = 0; B < 2; ++B)
            #pragma unroll
            for (int r = 0; r < 16; ++r) {
                st[B][r] = exp2_fast(st[B][r] - m_run);
                ts += st[B][r];
            }
        l_part += ts;

        // ---- P^T B-frags in-register: 16 cvt_pk + 8 permlane32_swap (T12) ----
        Frag pb[2][2];
        #pragma unroll
        for (int B = 0; B < 2; ++B)
            #pragma unroll
            for (int kbv = 0; kbv < 2; ++kbv) {
                unsigned P = pack2bf(st[B][8 * kbv + 0], st[B][8 * kbv + 1]);
                unsigned Q = pack2bf(st[B][8 * kbv + 2], st[B][8 * kbv + 3]);
                unsigned R = pack2bf(st[B][8 * kbv + 4], st[B][8 * kbv + 5]);
                unsigned S = pack2bf(st[B][8 * kbv + 6], st[B][8 * kbv + 7]);
                pl32swap(P, R);   // P -> w0, R -> w2 (both halves correct)
                pl32swap(Q, S);   // Q -> w1, S -> w3
                pb[B][kbv].u4.x = P;
                pb[B][kbv].u4.y = Q;
                pb[B][kbv].u4.z = R;
                pb[B][kbv].u4.w = S;
            }

        // ---- PV: acc[db] += V^T-chunk x P^T-chunk, 8 x mfma 32x32x16 ----
        __builtin_amdgcn_s_setprio(1);
        #pragma unroll
        for (int db = 0; db < 2; ++db)
            #pragma unroll
            for (int B = 0; B < 2; ++B)
                #pragma unroll
                for (int kbv = 0; kbv < 2; ++kbv) {
                    Frag vf;  // V^T[d = db*32 + (l&31)][kv = B*32 + kbv*16 + 8*hh + i]
                    vf.u4 = *reinterpret_cast<const uint4*>(
                        &vbuf[(db * 32 + (l & 31)) * 64 + (((B << 2) | (kbv << 1) | hh) ^ swz) * 8]);
                    acc[db] = mfma32(vf.b, pb[B][kbv].b, acc[db]);
                }
        __builtin_amdgcn_s_setprio(0);

        __syncthreads();   // drains vmcnt (stage t+1 done) + lgkm; guards buffer swap
        cur ^= 1;
    }

    // final l across halves; normalize per-lane
    l_part += __shfl_xor(l_part, 32);
    const float inv = 1.f / l_part;

    // epilogue: transpose O through LDS (kvs is free) for coalesced stores
    ushort_t* olds = &kvs[0][0];    // [256 rows][8 granules 16B], swizzled
    const int rowq = w * 32 + qc;
    #pragma unroll
    for (int db = 0; db < 2; ++db)
        #pragma unroll
        for (int rq = 0; rq < 4; ++rq) {
            uint2 ov;
            ov.x = pack2bf(acc[db][4 * rq + 0] * inv, acc[db][4 * rq + 1] * inv);
            ov.y = pack2bf(acc[db][4 * rq + 2] * inv, acc[db][4 * rq + 3] * inv);
            const int gL = db * 4 + rq;                     // d granule (8 ush)
            const int phys = gL ^ (qc & 7);
            *reinterpret_cast<uint2*>(&olds[(rowq * 8 + phys) * 8 + 4 * hh]) = ov;
        }
    __syncthreads();

    const size_t obase = ((size_t)(bh >> 4) * 2048 + qb * 256) * 1024 + hd * 64;
    #pragma unroll
    for (int p = 0; p < 4; ++p) {
        const int G = p * 512 + tid;
        const int row = G >> 3, sl = G & 7;
        const int phys = sl ^ (row & 7);
        uint4 v = *reinterpret_cast<const uint4*>(&olds[(row * 8 + phys) * 8]);
        *reinterpret_cast<uint4*>(out + obase + (size_t)row * 1024 + sl * 8) = v;
    }
}

// ---------------------------------------------------------------- launch
extern "C" void kernel_launch(void* const* d_in, const int* in_sizes, int n_in,
                              void* d_out, int out_size, void* d_ws, size_t ws_size,
                              hipStream_t stream)
{
    (void)in_sizes; (void)n_in; (void)out_size; (void)ws_size;
    const float* x     = (const float*)d_in[0];
    const float* gamma = (const float*)d_in[1];
    const float* w_q   = (const float*)d_in[2];
    const float* w_kv  = (const float*)d_in[3];
    const float* w_out = (const float*)d_in[4];
    const float* nkv   = (const float*)d_in[5];
    float* out = (float*)d_out;

    char* ws = (char*)d_ws;
    ushort_t* xn    = (ushort_t*)(ws);               // 16 MB  [8192,1024] bf16
    ushort_t* wqkvT = (ushort_t*)(ws + 16777216);    //  6 MB  [3072,1024] (q|k|v)
    ushort_t* woT   = (ushort_t*)(ws + 23068672);    //  2 MB  [1024,1024]
    ushort_t* qh    = (ushort_t*)(ws + 25165824);    // 16 MB  [b,h,2048,64] (kh follows)
    ushort_t* vtb   = (ushort_t*)(ws + 58720256);    // 16 MB  [b,h,64,2048]
    ushort_t* ao    = xn;                            // attn output reuses xn
    ushort_t* kh    = qh + 8388608;

    ln_kernel<<<dim3(8192), dim3(256), 0, stream>>>(x, gamma, xn);
    wt_kernel<<<dim3(32, 32), dim3(32, 8), 0, stream>>>(w_q,  wqkvT, 1024, 1024);
    wt_kernel<<<dim3(64, 32), dim3(32, 8), 0, stream>>>(w_kv, wqkvT + 1048576, 1024, 2048);
    wt_kernel<<<dim3(32, 32), dim3(32, 8), 0, stream>>>(w_out, woT, 1024, 1024);

    // fused QKV projection: N = 3072
    gemm_kernel<0><<<dim3(64, 24), dim3(256), 0, stream>>>(xn, wqkvT, qh, vtb, nullptr);

    attn_kernel<<<dim3(64, 8), dim3(512), 0, stream>>>(qh, kh, vtb, nkv, ao);

    gemm_kernel<2><<<dim3(64, 8), dim3(256), 0, stream>>>(ao, woT, nullptr, nullptr, out);
}